// Round 1
// baseline (449.032 us; speedup 1.0000x reference)
//
#include <hip/hip_runtime.h>

// Problem constants (from setup_inputs)
#define BS 8
#define NN 4096
#define NB 8
#define NR 64
#define ND 256
#define TN 128        // n-rows per tile
#define QPAD 264      // row stride (elems) for qbf/Kb: 256 + 8 pad -> 528 B, 16B-aligned, 2-way banks
#define SPAD 72       // row stride (elems) for Vt/Ssm: 64 + 8 pad -> 144 B, 16B-aligned, 2-way banks

typedef __attribute__((ext_vector_type(8))) short bf16x8;
typedef __attribute__((ext_vector_type(4))) float f32x4;

__device__ __forceinline__ unsigned short f2bf(float f) {
    unsigned int u = __builtin_bit_cast(unsigned int, f);
    u += 0x7fffu + ((u >> 16) & 1u);          // round-to-nearest-even
    return (unsigned short)(u >> 16);
}
__device__ __forceinline__ float bf2f(unsigned short h) {
    unsigned int u = ((unsigned int)h) << 16;
    return __builtin_bit_cast(float, u);
}

// grid = 256 blocks (64 (s,b) pairs x 4 chunks), block = 512 threads (8 waves).
// Each block: stage K/V/a once, then 8 tiles of TN=128 q-rows:
//   S = q @ K^T (MFMA bf16), W = S * a[r]/max(||q_n||,eps), O = W @ V (MFMA), out = q*O.
__global__ __launch_bounds__(512, 2)
void holo_read_kernel(const float* __restrict__ q,
                      const float* __restrict__ pmK,
                      const float* __restrict__ pmV,
                      const float* __restrict__ pma,
                      float* __restrict__ out)
{
    __shared__ __attribute__((aligned(16))) unsigned short qbf[TN][QPAD];  // raw q, bf16
    __shared__ __attribute__((aligned(16))) unsigned short Kb[NR][QPAD];   // K, bf16
    __shared__ __attribute__((aligned(16))) unsigned short Vt[ND][SPAD];   // V transposed [d][r]
    __shared__ __attribute__((aligned(16))) unsigned short Ssm[TN][SPAD];  // W = scaled scores, bf16
    __shared__ float invn[TN];   // 1/max(||q_n||, eps)
    __shared__ float a_sh[NR];

    const int tid  = threadIdx.x;
    const int lane = tid & 63;
    const int w    = tid >> 6;      // wave id 0..7
    const int ln15 = lane & 15;
    const int quad = lane >> 4;

    const int sbi   = blockIdx.x & 63;   // same-sb blocks 64 apart -> same XCD (RR%8)
    const int chunk = blockIdx.x >> 6;   // 0..3
    const int s     = sbi >> 3;
    const int b     = sbi & 7;

    // ---- stage a, K, V (once per block) ----
    if (tid < NR) a_sh[tid] = pma[sbi * NR + tid];
    const size_t kvbase = (size_t)sbi * NR * ND;
    for (int rr = w; rr < NR; rr += 8) {
        const float4 kv = *(const float4*)&pmK[kvbase + (size_t)rr * ND + lane * 4];
        ushort4 uk;
        uk.x = f2bf(kv.x); uk.y = f2bf(kv.y); uk.z = f2bf(kv.z); uk.w = f2bf(kv.w);
        *(ushort4*)&Kb[rr][lane * 4] = uk;
        const float4 vv = *(const float4*)&pmV[kvbase + (size_t)rr * ND + lane * 4];
        Vt[lane * 4 + 0][rr] = f2bf(vv.x);
        Vt[lane * 4 + 1][rr] = f2bf(vv.y);
        Vt[lane * 4 + 2][rr] = f2bf(vv.z);
        Vt[lane * 4 + 3][rr] = f2bf(vv.w);
    }
    __syncthreads();

    for (int t = 0; t < 8; ++t) {
        const int n0 = (chunk * 8 + t) * TN;

        // ---- Phase A: stage q tile (coalesced float4), row norms via wave reduce ----
        for (int base = 0; base < 16; base += 4) {
            float4 bufv[4];
            #pragma unroll
            for (int j = 0; j < 4; ++j) {
                const int row = (base + j) * 8 + w;
                const size_t gb = ((size_t)(s * NN + n0 + row) * NB + b) * ND;
                bufv[j] = *(const float4*)&q[gb + lane * 4];
            }
            #pragma unroll
            for (int j = 0; j < 4; ++j) {
                const int row = (base + j) * 8 + w;
                const float4 qv = bufv[j];
                float ss = qv.x * qv.x + qv.y * qv.y + qv.z * qv.z + qv.w * qv.w;
                #pragma unroll
                for (int m = 1; m < 64; m <<= 1) ss += __shfl_xor(ss, m, 64);
                if (lane == 0) invn[row] = 1.0f / fmaxf(sqrtf(ss), 1e-8f);
                ushort4 uq;
                uq.x = f2bf(qv.x); uq.y = f2bf(qv.y); uq.z = f2bf(qv.z); uq.w = f2bf(qv.w);
                *(ushort4*)&qbf[row][lane * 4] = uq;
            }
        }
        __syncthreads();

        // ---- GEMM1: S[16w..16w+15][0..63] = q_tile @ K^T ----
        {
            f32x4 accS[4];
            #pragma unroll
            for (int rt = 0; rt < 4; ++rt) accS[rt] = (f32x4){0.f, 0.f, 0.f, 0.f};
            #pragma unroll
            for (int kk = 0; kk < 8; ++kk) {
                const bf16x8 afr = *(const bf16x8*)&qbf[16 * w + ln15][kk * 32 + quad * 8];
                #pragma unroll
                for (int rt = 0; rt < 4; ++rt) {
                    const bf16x8 bfr = *(const bf16x8*)&Kb[rt * 16 + ln15][kk * 32 + quad * 8];
                    accS[rt] = __builtin_amdgcn_mfma_f32_16x16x32_bf16(afr, bfr, accS[rt], 0, 0, 0);
                }
            }
            // scale by a[r] * invnorm[n], store W bf16 to LDS (C-layout: col r=ln15, row n=quad*4+reg)
            float inr[4];
            #pragma unroll
            for (int reg = 0; reg < 4; ++reg) inr[reg] = invn[16 * w + quad * 4 + reg];
            #pragma unroll
            for (int rt = 0; rt < 4; ++rt) {
                const float ar = a_sh[rt * 16 + ln15];
                #pragma unroll
                for (int reg = 0; reg < 4; ++reg) {
                    Ssm[16 * w + quad * 4 + reg][rt * 16 + ln15] = f2bf(accS[rt][reg] * ar * inr[reg]);
                }
            }
        }
        __syncthreads();

        // ---- GEMM2: O[16w..16w+15][0..255] = W @ V, epilogue out = q*O ----
        {
            f32x4 accO[16];
            #pragma unroll
            for (int dt = 0; dt < 16; ++dt) accO[dt] = (f32x4){0.f, 0.f, 0.f, 0.f};
            #pragma unroll
            for (int kt = 0; kt < 2; ++kt) {
                const bf16x8 aw = *(const bf16x8*)&Ssm[16 * w + ln15][kt * 32 + quad * 8];
                #pragma unroll
                for (int dt = 0; dt < 16; ++dt) {
                    const bf16x8 bv = *(const bf16x8*)&Vt[dt * 16 + ln15][kt * 32 + quad * 8];
                    accO[dt] = __builtin_amdgcn_mfma_f32_16x16x32_bf16(aw, bv, accO[dt], 0, 0, 0);
                }
            }
            #pragma unroll
            for (int reg = 0; reg < 4; ++reg) {
                const int n = 16 * w + quad * 4 + reg;
                const size_t gb = ((size_t)(s * NN + n0 + n) * NB + b) * ND;
                #pragma unroll
                for (int dt = 0; dt < 16; ++dt) {
                    const int d = dt * 16 + ln15;
                    out[gb + d] = bf2f(qbf[n][d]) * accO[dt][reg];
                }
            }
        }
        __syncthreads();  // protect qbf/Ssm before next tile's staging
    }
}

extern "C" void kernel_launch(void* const* d_in, const int* in_sizes, int n_in,
                              void* d_out, int out_size, void* d_ws, size_t ws_size,
                              hipStream_t stream) {
    const float* q   = (const float*)d_in[0];
    const float* pmK = (const float*)d_in[1];
    const float* pmV = (const float*)d_in[2];
    const float* pma = (const float*)d_in[3];
    float* out = (float*)d_out;
    (void)in_sizes; (void)n_in; (void)out_size; (void)d_ws; (void)ws_size;
    hipLaunchKernelGGL(holo_read_kernel, dim3(256), dim3(512), 0, stream,
                       q, pmK, pmV, pma, out);
}